// Round 19
// baseline (130.042 us; speedup 1.0000x reference)
//
#include <hip/hip_runtime.h>
#include <hip/hip_bf16.h>

#define BB   256
#define NIN  1152
#define OO   10
#define IL   8
#define OL   16
#define ROW  (OO*OL)      // 160
#define EPSQ 1e-7f
#define NT   4            // n-tile per build block
#define BT   32           // b-tile per build block
#define GNC  72           // gemm0 n-chunks (16 n each)

typedef unsigned short ushx8 __attribute__((ext_vector_type(8)));

__device__ __forceinline__ float bf2f(unsigned short h) {
    unsigned u = ((unsigned)h) << 16;
    return __builtin_bit_cast(float, u);
}

// K1: build u_hat[b][n][o*16+k] in bf16. VERIFIED round-13/14 (~9us).
__global__ __launch_bounds__(160) void caps_build(
    const float* __restrict__ x, const float* __restrict__ w,
    unsigned short* __restrict__ u)
{
    __shared__ float4 wl4[NT][321];
    __shared__ float4 xl4[BT * 8];
    const int t  = threadIdx.x;
    const int n0 = blockIdx.x * NT;
    const int b0 = blockIdx.y * BT;

    const float4* wg = reinterpret_cast<const float4*>(w) + (size_t)n0 * 320;
    #pragma unroll
    for (int jj = 0; jj < 8; ++jj) {
        const int j   = t + jj * 160;
        const int row = j / 320;
        const int lin = j - row * 320;
        const int o   = lin >> 5;
        const int rem = lin & 31;
        const int i   = rem >> 2;
        const int kh  = rem & 3;
        wl4[row][(o << 5) | ((i ^ (o & 1)) << 2) | kh] = wg[j];
    }
    const float4* xg = reinterpret_cast<const float4*>(x);
    {
        int j = t;
        xl4[j] = xg[((size_t)(b0 + (j >> 3)) * NIN + n0) * 2 + (j & 7)];
        j = t + 160;
        if (j < BT * 8)
            xl4[j] = xg[((size_t)(b0 + (j >> 3)) * NIN + n0) * 2 + (j & 7)];
    }
    __syncthreads();

    const int nl = t / 40;
    const int r  = t - nl * 40;
    const int hh = r / 20;
    const int s  = r - hh * 20;
    const int o  = s >> 1;
    const int k8 = s & 1;
    const int p  = o & 1;
    const float4* wbase = &wl4[nl][(o << 5) | (k8 << 1)];
    const float4* xbase = &xl4[(hh * 16) * 8 + nl * 2];
    unsigned short* ub = u + ((size_t)(b0 + hh * 16) * NIN + n0 + nl) * ROW
                           + o * OL + k8 * 8;
    const size_t ustride = (size_t)NIN * ROW;

    for (int bl = 0; bl < 16; bl += 4) {
        float xv[4][IL];
        #pragma unroll
        for (int bb = 0; bb < 4; ++bb) {
            const float4 x0 = xbase[(bl + bb) * 8];
            const float4 x1 = xbase[(bl + bb) * 8 + 1];
            xv[bb][0] = x0.x; xv[bb][1] = x0.y; xv[bb][2] = x0.z; xv[bb][3] = x0.w;
            xv[bb][4] = x1.x; xv[bb][5] = x1.y; xv[bb][6] = x1.z; xv[bb][7] = x1.w;
        }

        float acc[4][8];
        #pragma unroll
        for (int bb = 0; bb < 4; ++bb)
            #pragma unroll
            for (int j = 0; j < 8; ++j) acc[bb][j] = 0.f;

        #pragma unroll
        for (int i = 0; i < IL; ++i) {
            const float4 wlo = wbase[(i ^ p) << 2];
            const float4 whi = wbase[((i ^ p) << 2) | 1];
            const float wv[8] = {wlo.x, wlo.y, wlo.z, wlo.w, whi.x, whi.y, whi.z, whi.w};
            #pragma unroll
            for (int bb = 0; bb < 4; ++bb)
                #pragma unroll
                for (int j = 0; j < 8; ++j)
                    acc[bb][j] = fmaf(wv[j], xv[bb][i], acc[bb][j]);
        }

        #pragma unroll
        for (int bb = 0; bb < 4; ++bb) {
            union { ushx8 v; __hip_bfloat162 h[4]; } pk;
            #pragma unroll
            for (int j = 0; j < 4; ++j)
                pk.h[j] = __float22bfloat162_rn(make_float2(acc[bb][2*j], acc[bb][2*j+1]));
            *reinterpret_cast<ushx8*>(ub + (size_t)(bl + bb) * ustride) = pk.v;
        }
    }
}

// K2: split-K GEMM for iter0's reduction: psum[nc][b][160] = sum over the
// chunk's 16 n of u_hat (fp32), computed straight from x and w — replaces a
// 94 MB u-sweep with 15 MB of L2-resident input reads. NO LDS (no conflict
// surface), no w-hoist assumption: per n, 16 w-float4 broadcast loads + 4 x
// loads; acc[2][8] only (~64 VGPR). Block 320 = 16 bq x 20 oct; bq owns
// b = b0+bq and b0+bq+16. Grid (8, 72) = 576 blocks.
__global__ __launch_bounds__(320) void caps_gemm0(
    const float* __restrict__ x, const float* __restrict__ w,
    float* __restrict__ psum)
{
    const int t   = threadIdx.x;
    const int bq  = t / 20;
    const int oct = t - bq * 20;
    const int o   = oct >> 1;
    const int k8  = oct & 1;
    const int b1  = blockIdx.x * 32 + bq;
    const int b2  = b1 + 16;
    const int nc  = blockIdx.y;
    const int n0  = nc * 16;

    const float* wq  = w + (size_t)n0 * 1280 + o * 128 + k8 * 8;
    const float* xq1 = x + ((size_t)b1 * NIN + n0) * 8;
    const float* xq2 = x + ((size_t)b2 * NIN + n0) * 8;

    float a0[8], a1[8];
    #pragma unroll
    for (int j = 0; j < 8; ++j) { a0[j] = 0.f; a1[j] = 0.f; }

    for (int nn = 0; nn < 16; ++nn) {
        const float4 xa0 = *reinterpret_cast<const float4*>(xq1 + nn * 8);
        const float4 xa1 = *reinterpret_cast<const float4*>(xq1 + nn * 8 + 4);
        const float4 xb0 = *reinterpret_cast<const float4*>(xq2 + nn * 8);
        const float4 xb1 = *reinterpret_cast<const float4*>(xq2 + nn * 8 + 4);
        const float xv0[IL] = {xa0.x, xa0.y, xa0.z, xa0.w, xa1.x, xa1.y, xa1.z, xa1.w};
        const float xv1[IL] = {xb0.x, xb0.y, xb0.z, xb0.w, xb1.x, xb1.y, xb1.z, xb1.w};

        const float* wn = wq + (size_t)nn * 1280;
        #pragma unroll
        for (int i = 0; i < IL; ++i) {
            const float4 wlo = *reinterpret_cast<const float4*>(wn + i * 16);
            const float4 whi = *reinterpret_cast<const float4*>(wn + i * 16 + 4);
            a0[0] = fmaf(wlo.x, xv0[i], a0[0]);  a1[0] = fmaf(wlo.x, xv1[i], a1[0]);
            a0[1] = fmaf(wlo.y, xv0[i], a0[1]);  a1[1] = fmaf(wlo.y, xv1[i], a1[1]);
            a0[2] = fmaf(wlo.z, xv0[i], a0[2]);  a1[2] = fmaf(wlo.z, xv1[i], a1[2]);
            a0[3] = fmaf(wlo.w, xv0[i], a0[3]);  a1[3] = fmaf(wlo.w, xv1[i], a1[3]);
            a0[4] = fmaf(whi.x, xv0[i], a0[4]);  a1[4] = fmaf(whi.x, xv1[i], a1[4]);
            a0[5] = fmaf(whi.y, xv0[i], a0[5]);  a1[5] = fmaf(whi.y, xv1[i], a1[5]);
            a0[6] = fmaf(whi.z, xv0[i], a0[6]);  a1[6] = fmaf(whi.z, xv1[i], a1[6]);
            a0[7] = fmaf(whi.w, xv0[i], a0[7]);  a1[7] = fmaf(whi.w, xv1[i], a1[7]);
        }
    }

    float* p1 = psum + ((size_t)nc * BB + b1) * ROW + oct * 8;
    float* p2 = psum + ((size_t)nc * BB + b2) * ROW + oct * 8;
    *reinterpret_cast<float4*>(p1)     = make_float4(a0[0], a0[1], a0[2], a0[3]);
    *reinterpret_cast<float4*>(p1 + 4) = make_float4(a0[4], a0[5], a0[6], a0[7]);
    *reinterpret_cast<float4*>(p2)     = make_float4(a1[0], a1[1], a1[2], a1[3]);
    *reinterpret_cast<float4*>(p2 + 4) = make_float4(a1[4], a1[5], a1[6], a1[7]);
}

// K3: sum psum chunks (72), *0.1 + bias, squash -> v0. (verified round-16)
__global__ __launch_bounds__(192) void caps_squash0(
    const float* __restrict__ psum, const float* __restrict__ bias,
    float* __restrict__ v0)
{
    const int t = threadIdx.x;
    if (t >= ROW) return;
    const int b = blockIdx.x;

    float s0 = 0.f, s1 = 0.f, s2 = 0.f, s3 = 0.f;
    const float* pt = psum + (size_t)b * ROW + t;
    #pragma unroll
    for (int ch = 0; ch < GNC; ch += 4) {
        s0 += pt[(size_t)(ch + 0) * BB * ROW];
        s1 += pt[(size_t)(ch + 1) * BB * ROW];
        s2 += pt[(size_t)(ch + 2) * BB * ROW];
        s3 += pt[(size_t)(ch + 3) * BB * ROW];
    }
    const float s = 0.1f * ((s0 + s1) + (s2 + s3)) + bias[t];

    float d = s * s;
    d += __shfl_xor(d, 1, 16);
    d += __shfl_xor(d, 2, 16);
    d += __shfl_xor(d, 4, 16);
    d += __shfl_xor(d, 8, 16);
    const float f = d / ((1.f + d) * sqrtf(d + EPSQ));
    v0[(size_t)b * ROW + t] = f * s;
}

// K4: routing iterations 1,2 fused (verified round-15/16/17 code, untouched).
__global__ __launch_bounds__(768) void caps_route2(
    const unsigned short* __restrict__ u, const float* __restrict__ bias,
    const float* __restrict__ v0g, float* __restrict__ outv)
{
    __shared__ float lds[12][ROW];
    __shared__ float vbuf[ROW];
    const int t  = threadIdx.x;
    const int q  = t & 3;
    const int g  = t >> 2;     // 0..191
    const int wv = t >> 6;     // 0..11
    const int b  = blockIdx.x;
    const unsigned short* ub = u + (size_t)b * NIN * ROW;

    float bsv = 0.f;
    float vprev = 0.f;
    if (t < ROW) {
        bsv = bias[t];
        const float v = v0g[(size_t)b * ROW + t];
        vbuf[t] = v;
        vprev = v;
    }
    __syncthreads();

    #pragma unroll
    for (int iter = 1; iter < 3; ++iter) {
        float sp[5][8];
        #pragma unroll
        for (int j = 0; j < 5; ++j)
            #pragma unroll
            for (int e = 0; e < 8; ++e) sp[j][e] = 0.f;

        float vs[5][8];
        #pragma unroll
        for (int j = 0; j < 5; ++j) {
            #pragma unroll
            for (int e = 0; e < 8; ++e) vs[j][e] = vbuf[(q + 4 * j) * 8 + e];
        }

        for (int m = 0; m < 6; ++m) {
            const unsigned short* un = ub + (size_t)(g + m * 192) * ROW;
            float uf[5][8];
            #pragma unroll
            for (int j = 0; j < 5; ++j) {
                const ushx8 raw = *reinterpret_cast<const ushx8*>(un + (q + 4 * j) * 8);
                #pragma unroll
                for (int e = 0; e < 8; ++e) uf[j][e] = bf2f(raw[e]);
            }

            float d[5], dd[5];
            #pragma unroll
            for (int j = 0; j < 5; ++j) {
                float acc = uf[j][0] * vs[j][0];
                #pragma unroll
                for (int e = 1; e < 8; ++e) acc = fmaf(uf[j][e], vs[j][e], acc);
                acc += __shfl_xor(acc, 1, 4);
                d[j] = acc;
            }
            #pragma unroll
            for (int j = 0; j < 5; ++j) dd[j] = __shfl_xor(d[j], 2, 4);

            float mx = fmaxf(d[0], dd[0]);
            #pragma unroll
            for (int j = 1; j < 5; ++j) mx = fmaxf(mx, fmaxf(d[j], dd[j]));
            float se = 0.f, e_[5];
            #pragma unroll
            for (int j = 0; j < 5; ++j) {
                e_[j] = __expf(d[j] - mx);
                se += e_[j] + __expf(dd[j] - mx);
            }
            const float rr = 1.f / se;
            #pragma unroll
            for (int j = 0; j < 5; ++j) {
                const float c = e_[j] * rr;
                #pragma unroll
                for (int e = 0; e < 8; ++e)
                    sp[j][e] = fmaf(c, uf[j][e], sp[j][e]);
            }
        }

        #pragma unroll
        for (int j = 0; j < 5; ++j)
            #pragma unroll
            for (int e = 0; e < 8; ++e) {
                #pragma unroll
                for (int msk = 4; msk <= 32; msk <<= 1)
                    sp[j][e] += __shfl_xor(sp[j][e], msk);
            }
        if ((t & 63) < 4) {
            #pragma unroll
            for (int j = 0; j < 5; ++j)
                #pragma unroll
                for (int e = 0; e < 8; ++e)
                    lds[wv][(q + 4 * j) * 8 + e] = sp[j][e];
        }
        __syncthreads();

        if (t < ROW) {
            float ssum = 0.f;
            #pragma unroll
            for (int wvi = 0; wvi < 12; ++wvi) ssum += lds[wvi][t];
            const float sv = ssum + bsv;

            float dq = sv * sv;
            dq += __shfl_xor(dq, 1, 16);
            dq += __shfl_xor(dq, 2, 16);
            dq += __shfl_xor(dq, 4, 16);
            dq += __shfl_xor(dq, 8, 16);
            const float f = dq / ((1.f + dq) * sqrtf(dq + EPSQ));
            const float v = f * sv;

            if (iter == 1) { vbuf[t] = v + vprev; }
            else           { outv[(size_t)b * ROW + t] = v; }
        }
        __syncthreads();
    }
}

extern "C" void kernel_launch(void* const* d_in, const int* in_sizes, int n_in,
                              void* d_out, int out_size, void* d_ws, size_t ws_size,
                              hipStream_t stream) {
    const float* x    = (const float*)d_in[0]; // (B, NIN, 8, 1)
    const float* w    = (const float*)d_in[1]; // (1, NIN, O, 8, 16)
    const float* bias = (const float*)d_in[2]; // (1, 1, O, 16, 1)
    float* out = (float*)d_out;                // (B, 1, O, 16, 1)

    unsigned short* u = (unsigned short*)d_ws;                        // 94.4 MB
    float* psum = (float*)((char*)d_ws + (size_t)BB * NIN * ROW * 2); // 11.8 MB
    float* v0   = psum + (size_t)GNC * BB * ROW;                      // 160 KB

    caps_build<<<dim3(NIN / NT, BB / BT), 160, 0, stream>>>(x, w, u);
    caps_gemm0<<<dim3(BB / 32, GNC), 320, 0, stream>>>(x, w, psum);
    caps_squash0<<<BB, 192, 0, stream>>>(psum, bias, v0);
    caps_route2<<<BB, 768, 0, stream>>>(u, bias, v0, out);
}

// Round 20
// 84.394 us; speedup vs baseline: 1.5409x; 1.5409x over previous
//
#include <hip/hip_runtime.h>
#include <hip/hip_bf16.h>

#define BB   256
#define NIN  1152
#define OO   10
#define IL   8
#define OL   16
#define ROW  (OO*OL)      // 160
#define EPSQ 1e-7f
#define NT   4            // n-tile per build block
#define BT   32           // b-tile per build block
#define GNC  72           // gemm0 K-splits (16 n each)

typedef unsigned short ushx8 __attribute__((ext_vector_type(8)));
typedef short s16x8 __attribute__((ext_vector_type(8)));
typedef float f32x4 __attribute__((ext_vector_type(4)));

__device__ __forceinline__ float bf2f(unsigned short h) {
    unsigned u = ((unsigned)h) << 16;
    return __builtin_bit_cast(float, u);
}
__device__ __forceinline__ unsigned short f2bf(float f) {
    unsigned u = __builtin_bit_cast(unsigned, f);
    u += 0x7FFFu + ((u >> 16) & 1u);   // RNE
    return (unsigned short)(u >> 16);
}

// K1: build u_hat[b][n][o*16+k] in bf16. VERIFIED round-13/14 (~9us).
__global__ __launch_bounds__(160) void caps_build(
    const float* __restrict__ x, const float* __restrict__ w,
    unsigned short* __restrict__ u)
{
    __shared__ float4 wl4[NT][321];
    __shared__ float4 xl4[BT * 8];
    const int t  = threadIdx.x;
    const int n0 = blockIdx.x * NT;
    const int b0 = blockIdx.y * BT;

    const float4* wg = reinterpret_cast<const float4*>(w) + (size_t)n0 * 320;
    #pragma unroll
    for (int jj = 0; jj < 8; ++jj) {
        const int j   = t + jj * 160;
        const int row = j / 320;
        const int lin = j - row * 320;
        const int o   = lin >> 5;
        const int rem = lin & 31;
        const int i   = rem >> 2;
        const int kh  = rem & 3;
        wl4[row][(o << 5) | ((i ^ (o & 1)) << 2) | kh] = wg[j];
    }
    const float4* xg = reinterpret_cast<const float4*>(x);
    {
        int j = t;
        xl4[j] = xg[((size_t)(b0 + (j >> 3)) * NIN + n0) * 2 + (j & 7)];
        j = t + 160;
        if (j < BT * 8)
            xl4[j] = xg[((size_t)(b0 + (j >> 3)) * NIN + n0) * 2 + (j & 7)];
    }
    __syncthreads();

    const int nl = t / 40;
    const int r  = t - nl * 40;
    const int hh = r / 20;
    const int s  = r - hh * 20;
    const int o  = s >> 1;
    const int k8 = s & 1;
    const int p  = o & 1;
    const float4* wbase = &wl4[nl][(o << 5) | (k8 << 1)];
    const float4* xbase = &xl4[(hh * 16) * 8 + nl * 2];
    unsigned short* ub = u + ((size_t)(b0 + hh * 16) * NIN + n0 + nl) * ROW
                           + o * OL + k8 * 8;
    const size_t ustride = (size_t)NIN * ROW;

    for (int bl = 0; bl < 16; bl += 4) {
        float xv[4][IL];
        #pragma unroll
        for (int bb = 0; bb < 4; ++bb) {
            const float4 x0 = xbase[(bl + bb) * 8];
            const float4 x1 = xbase[(bl + bb) * 8 + 1];
            xv[bb][0] = x0.x; xv[bb][1] = x0.y; xv[bb][2] = x0.z; xv[bb][3] = x0.w;
            xv[bb][4] = x1.x; xv[bb][5] = x1.y; xv[bb][6] = x1.z; xv[bb][7] = x1.w;
        }

        float acc[4][8];
        #pragma unroll
        for (int bb = 0; bb < 4; ++bb)
            #pragma unroll
            for (int j = 0; j < 8; ++j) acc[bb][j] = 0.f;

        #pragma unroll
        for (int i = 0; i < IL; ++i) {
            const float4 wlo = wbase[(i ^ p) << 2];
            const float4 whi = wbase[((i ^ p) << 2) | 1];
            const float wv[8] = {wlo.x, wlo.y, wlo.z, wlo.w, whi.x, whi.y, whi.z, whi.w};
            #pragma unroll
            for (int bb = 0; bb < 4; ++bb)
                #pragma unroll
                for (int j = 0; j < 8; ++j)
                    acc[bb][j] = fmaf(wv[j], xv[bb][i], acc[bb][j]);
        }

        #pragma unroll
        for (int bb = 0; bb < 4; ++bb) {
            union { ushx8 v; __hip_bfloat162 h[4]; } pk;
            #pragma unroll
            for (int j = 0; j < 4; ++j)
                pk.h[j] = __float22bfloat162_rn(make_float2(acc[bb][2*j], acc[bb][2*j+1]));
            *reinterpret_cast<ushx8*>(ub + (size_t)(bl + bb) * ustride) = pk.v;
        }
    }
}

// K2a: pack w -> B-fragment order (VERIFIED round 9):
// wp[(n*10+o)*16 + l][e] = w[n][o][e][l] (bf16)
__global__ __launch_bounds__(256) void prep_w(const float* __restrict__ w,
                                              short* __restrict__ wp)
{
    const int id = blockIdx.x * 256 + threadIdx.x;   // < 1152*10*16
    const int l  = id & 15;
    const int no = id >> 4;
    const float* src = w + (size_t)no * (IL * OL) + l;
    union { s16x8 v; unsigned short h[8]; } pk;
    #pragma unroll
    for (int i = 0; i < IL; ++i)
        pk.h[i] = f2bf(src[i * OL]);
    *reinterpret_cast<s16x8*>(wp + (size_t)id * 8) = pk.v;
}

// K2b: pack x -> A-fragment order (VERIFIED round 9):
// xp[n*256 + b][e] = x[b][n][e] (bf16); coalesced fp32 reads.
__global__ __launch_bounds__(256) void prep_x(const float* __restrict__ x,
                                              short* __restrict__ xp)
{
    const int id = blockIdx.x * 256 + threadIdx.x;   // < 256*1152
    const int n  = id % NIN;
    const int b  = id / NIN;
    const float4* src = reinterpret_cast<const float4*>(x + (size_t)id * IL);
    const float4 a = src[0], c = src[1];
    union { s16x8 v; unsigned short h[8]; } pk;
    pk.h[0] = f2bf(a.x); pk.h[1] = f2bf(a.y); pk.h[2] = f2bf(a.z); pk.h[3] = f2bf(a.w);
    pk.h[4] = f2bf(c.x); pk.h[5] = f2bf(c.y); pk.h[6] = f2bf(c.z); pk.h[7] = f2bf(c.w);
    *reinterpret_cast<s16x8*>(xp + ((size_t)n * BB + b) * 8) = pk.v;
}

// K3: MFMA split-K GEMM for iter0: psum[split][b][160] = sum over the split's
// 16 n of u_hat. Accumulators (10 x f32x4) force VGPR residency — the property
// every hoist-based attempt (r15-r19) lacked. Wave = 16-b m-tile; per K-step
// (4 n): A-frag = xp (lane l: b = b0+(l&15), n = n0+(l>>4), 8 i's), B-frag[o]
// = wp (lane l: col = l&15, same n, 8 i's), 10 mfma. C-layout (m89-verified):
// col = lane&15, row = (lane>>4)*4 + r. Grid (4, 72), 256 thr = 4 waves.
__global__ __launch_bounds__(256) void caps_gemm0(
    const short* __restrict__ xp, const short* __restrict__ wp,
    float* __restrict__ psum)
{
    const int t  = threadIdx.x;
    const int l  = t & 63;
    const int wv = t >> 6;
    const int b0 = (blockIdx.x * 4 + wv) * 16;
    const int n0 = blockIdx.y * 16;
    const int l15 = l & 15, lg = l >> 4;

    f32x4 acc[OO];
    #pragma unroll
    for (int o = 0; o < OO; ++o) acc[o] = (f32x4){0.f, 0.f, 0.f, 0.f};

    #pragma unroll
    for (int ks = 0; ks < 4; ++ks) {
        const int n = n0 + ks * 4 + lg;
        const s16x8 A = *reinterpret_cast<const s16x8*>(
            xp + ((size_t)n * BB + b0 + l15) * 8);
        #pragma unroll
        for (int o = 0; o < OO; ++o) {
            const s16x8 Bo = *reinterpret_cast<const s16x8*>(
                wp + (((size_t)n * OO + o) * 16 + l15) * 8);
            acc[o] = __builtin_amdgcn_mfma_f32_16x16x32_bf16(A, Bo, acc[o], 0, 0, 0);
        }
    }

    float* pb = psum + ((size_t)blockIdx.y * BB + b0 + lg * 4) * ROW + l15;
    #pragma unroll
    for (int o = 0; o < OO; ++o)
        #pragma unroll
        for (int r = 0; r < 4; ++r)
            pb[(size_t)r * ROW + o * OL] = acc[o][r];
}

// K4: sum psum splits (72), *0.1 + bias, squash -> v0. (verified round-19)
__global__ __launch_bounds__(192) void caps_squash0(
    const float* __restrict__ psum, const float* __restrict__ bias,
    float* __restrict__ v0)
{
    const int t = threadIdx.x;
    if (t >= ROW) return;
    const int b = blockIdx.x;

    float s0 = 0.f, s1 = 0.f, s2 = 0.f, s3 = 0.f;
    const float* pt = psum + (size_t)b * ROW + t;
    #pragma unroll
    for (int ch = 0; ch < GNC; ch += 4) {
        s0 += pt[(size_t)(ch + 0) * BB * ROW];
        s1 += pt[(size_t)(ch + 1) * BB * ROW];
        s2 += pt[(size_t)(ch + 2) * BB * ROW];
        s3 += pt[(size_t)(ch + 3) * BB * ROW];
    }
    const float s = 0.1f * ((s0 + s1) + (s2 + s3)) + bias[t];

    float d = s * s;
    d += __shfl_xor(d, 1, 16);
    d += __shfl_xor(d, 2, 16);
    d += __shfl_xor(d, 4, 16);
    d += __shfl_xor(d, 8, 16);
    const float f = d / ((1.f + d) * sqrtf(d + EPSQ));
    v0[(size_t)b * ROW + t] = f * s;
}

// K5: routing iterations 1,2 fused (verified round-15..19 code, untouched).
__global__ __launch_bounds__(768) void caps_route2(
    const unsigned short* __restrict__ u, const float* __restrict__ bias,
    const float* __restrict__ v0g, float* __restrict__ outv)
{
    __shared__ float lds[12][ROW];
    __shared__ float vbuf[ROW];
    const int t  = threadIdx.x;
    const int q  = t & 3;
    const int g  = t >> 2;     // 0..191
    const int wv = t >> 6;     // 0..11
    const int b  = blockIdx.x;
    const unsigned short* ub = u + (size_t)b * NIN * ROW;

    float bsv = 0.f;
    float vprev = 0.f;
    if (t < ROW) {
        bsv = bias[t];
        const float v = v0g[(size_t)b * ROW + t];
        vbuf[t] = v;
        vprev = v;
    }
    __syncthreads();

    #pragma unroll
    for (int iter = 1; iter < 3; ++iter) {
        float sp[5][8];
        #pragma unroll
        for (int j = 0; j < 5; ++j)
            #pragma unroll
            for (int e = 0; e < 8; ++e) sp[j][e] = 0.f;

        float vs[5][8];
        #pragma unroll
        for (int j = 0; j < 5; ++j) {
            #pragma unroll
            for (int e = 0; e < 8; ++e) vs[j][e] = vbuf[(q + 4 * j) * 8 + e];
        }

        for (int m = 0; m < 6; ++m) {
            const unsigned short* un = ub + (size_t)(g + m * 192) * ROW;
            float uf[5][8];
            #pragma unroll
            for (int j = 0; j < 5; ++j) {
                const ushx8 raw = *reinterpret_cast<const ushx8*>(un + (q + 4 * j) * 8);
                #pragma unroll
                for (int e = 0; e < 8; ++e) uf[j][e] = bf2f(raw[e]);
            }

            float d[5], dd[5];
            #pragma unroll
            for (int j = 0; j < 5; ++j) {
                float acc = uf[j][0] * vs[j][0];
                #pragma unroll
                for (int e = 1; e < 8; ++e) acc = fmaf(uf[j][e], vs[j][e], acc);
                acc += __shfl_xor(acc, 1, 4);
                d[j] = acc;
            }
            #pragma unroll
            for (int j = 0; j < 5; ++j) dd[j] = __shfl_xor(d[j], 2, 4);

            float mx = fmaxf(d[0], dd[0]);
            #pragma unroll
            for (int j = 1; j < 5; ++j) mx = fmaxf(mx, fmaxf(d[j], dd[j]));
            float se = 0.f, e_[5];
            #pragma unroll
            for (int j = 0; j < 5; ++j) {
                e_[j] = __expf(d[j] - mx);
                se += e_[j] + __expf(dd[j] - mx);
            }
            const float rr = 1.f / se;
            #pragma unroll
            for (int j = 0; j < 5; ++j) {
                const float c = e_[j] * rr;
                #pragma unroll
                for (int e = 0; e < 8; ++e)
                    sp[j][e] = fmaf(c, uf[j][e], sp[j][e]);
            }
        }

        #pragma unroll
        for (int j = 0; j < 5; ++j)
            #pragma unroll
            for (int e = 0; e < 8; ++e) {
                #pragma unroll
                for (int msk = 4; msk <= 32; msk <<= 1)
                    sp[j][e] += __shfl_xor(sp[j][e], msk);
            }
        if ((t & 63) < 4) {
            #pragma unroll
            for (int j = 0; j < 5; ++j)
                #pragma unroll
                for (int e = 0; e < 8; ++e)
                    lds[wv][(q + 4 * j) * 8 + e] = sp[j][e];
        }
        __syncthreads();

        if (t < ROW) {
            float ssum = 0.f;
            #pragma unroll
            for (int wvi = 0; wvi < 12; ++wvi) ssum += lds[wvi][t];
            const float sv = ssum + bsv;

            float dq = sv * sv;
            dq += __shfl_xor(dq, 1, 16);
            dq += __shfl_xor(dq, 2, 16);
            dq += __shfl_xor(dq, 4, 16);
            dq += __shfl_xor(dq, 8, 16);
            const float f = dq / ((1.f + dq) * sqrtf(dq + EPSQ));
            const float v = f * sv;

            if (iter == 1) { vbuf[t] = v + vprev; }
            else           { outv[(size_t)b * ROW + t] = v; }
        }
        __syncthreads();
    }
}

extern "C" void kernel_launch(void* const* d_in, const int* in_sizes, int n_in,
                              void* d_out, int out_size, void* d_ws, size_t ws_size,
                              hipStream_t stream) {
    const float* x    = (const float*)d_in[0]; // (B, NIN, 8, 1)
    const float* w    = (const float*)d_in[1]; // (1, NIN, O, 8, 16)
    const float* bias = (const float*)d_in[2]; // (1, 1, O, 16, 1)
    float* out = (float*)d_out;                // (B, 1, O, 16, 1)

    unsigned short* u = (unsigned short*)d_ws;                        // 94.4 MB
    short* xp = (short*)((char*)d_ws + (size_t)BB * NIN * ROW * 2);   // 4.7 MB
    short* wp = xp + (size_t)NIN * BB * 8;                            // 3.0 MB
    float* psum = (float*)(wp + (size_t)NIN * OO * 16 * 8);           // 11.8 MB
    float* v0   = psum + (size_t)GNC * BB * ROW;                      // 160 KB

    caps_build<<<dim3(NIN / NT, BB / BT), 160, 0, stream>>>(x, w, u);
    prep_x<<<(BB * NIN) / 256, 256, 0, stream>>>(x, xp);
    prep_w<<<(NIN * OO * 16) / 256, 256, 0, stream>>>(w, wp);
    caps_gemm0<<<dim3(4, GNC), 256, 0, stream>>>(xp, wp, psum);
    caps_squash0<<<BB, 192, 0, stream>>>(psum, bias, v0);
    caps_route2<<<BB, 768, 0, stream>>>(u, bias, v0, out);
}